// Round 1
// baseline (659.339 us; speedup 1.0000x reference)
//
#include <hip/hip_runtime.h>

#define NXK 2048
#define NYK 2048

__global__ __launch_bounds__(256) void interp2d_kernel(
    const float* __restrict__ xq, const float* __restrict__ yq,
    const float* __restrict__ xk, const float* __restrict__ yk,
    const float* __restrict__ f,  const float* __restrict__ fx,
    const float* __restrict__ fy, const float* __restrict__ fxy,
    float* __restrict__ out, int nq)
{
    int q = blockIdx.x * blockDim.x + threadIdx.x;
    if (q >= nq) return;

    float xv = xq[q];
    float yv = yq[q];

    // --- cell index, matching jnp.searchsorted(x, xq, side='right') then clip(1, n-1) ---
    // il = i-1 such that x[il] <= xv < x[il+1], il in [0, NXK-2]
    int il = (int)floorf(xv * (float)(NXK - 1));
    il = min(max(il, 0), NXK - 2);
    while (il < NXK - 2 && xv >= xk[il + 1]) ++il;
    while (il > 0 && xv < xk[il]) --il;

    int jl = (int)floorf(yv * (float)(NYK - 1));
    jl = min(max(jl, 0), NYK - 2);
    while (jl < NYK - 2 && yv >= yk[jl + 1]) ++jl;
    while (jl > 0 && yv < yk[jl]) --jl;

    float x0 = xk[il], x1 = xk[il + 1];
    float dx = x1 - x0;
    float dxi = (dx == 0.0f) ? 0.0f : 1.0f / dx;
    float tx = (xv - x0) * dxi;

    float y0 = yk[jl], y1 = yk[jl + 1];
    float dy = y1 - y0;
    float dyi = (dy == 0.0f) ? 0.0f : 1.0f / dy;
    float ty = (yv - y0) * dyi;

    // u = ttx^T @ A_CUBIC, A_CUBIC = [[1,0,0,0],[0,0,1,0],[-3,3,-2,-1],[2,-2,1,-1]]
    // u[c2] pairs with corner c2 = 2*jj + ii  (ii = x-offset, jj = y-offset)
    float u0 = 1.0f + tx * tx * (2.0f * tx - 3.0f);   // 1 - 3t^2 + 2t^3
    float u1 = tx * tx * (3.0f - 2.0f * tx);          // 3t^2 - 2t^3
    float u2 = tx * (1.0f + tx * (tx - 2.0f));        // t - 2t^2 + t^3
    float u3 = -tx * tx * (1.0f + tx);                // -t^2 - t^3  (note A[3,3] = -1!)

    // v = tty^T @ A_CUBIC; v[c1] pairs with array c1 in {f, fx*dx, fy*dy, fxy*dx*dy}
    float v0 = 1.0f + ty * ty * (2.0f * ty - 3.0f);
    float v1 = ty * ty * (3.0f - 2.0f * ty);
    float v2 = ty * (1.0f + ty * (ty - 2.0f));
    float v3 = -ty * ty * (1.0f + ty);

    long base = (long)il * NYK + jl;

    // corner order: c2=0 -> (ii=0,jj=0) = p[0]; c2=1 -> (ii=1,jj=0) = p[NYK];
    //               c2=2 -> (ii=0,jj=1) = p[1]; c2=3 -> (ii=1,jj=1) = p[NYK+1]
    const float* p = f + base;
    float sf   = u0 * p[0] + u2 * p[1] + u1 * p[NYK] + u3 * p[NYK + 1];
    p = fx + base;
    float sfx  = u0 * p[0] + u2 * p[1] + u1 * p[NYK] + u3 * p[NYK + 1];
    p = fy + base;
    float sfy  = u0 * p[0] + u2 * p[1] + u1 * p[NYK] + u3 * p[NYK + 1];
    p = fxy + base;
    float sfxy = u0 * p[0] + u2 * p[1] + u1 * p[NYK] + u3 * p[NYK + 1];

    out[q] = v0 * sf + v1 * (sfx * dx) + v2 * (sfy * dy) + v3 * (sfxy * (dx * dy));
}

extern "C" void kernel_launch(void* const* d_in, const int* in_sizes, int n_in,
                              void* d_out, int out_size, void* d_ws, size_t ws_size,
                              hipStream_t stream) {
    const float* xq  = (const float*)d_in[0];
    const float* yq  = (const float*)d_in[1];
    const float* xk  = (const float*)d_in[2];
    const float* yk  = (const float*)d_in[3];
    const float* f   = (const float*)d_in[4];
    const float* fx  = (const float*)d_in[5];
    const float* fy  = (const float*)d_in[6];
    const float* fxy = (const float*)d_in[7];
    float* out = (float*)d_out;

    int nq = in_sizes[0];
    int block = 256;
    int grid = (nq + block - 1) / block;
    interp2d_kernel<<<grid, block, 0, stream>>>(xq, yq, xk, yk, f, fx, fy, fxy, out, nq);
}

// Round 2
// 247.142 us; speedup vs baseline: 2.6679x; 2.6679x over previous
//
#include <hip/hip_runtime.h>
#include <hip/hip_fp16.h>

#define NXK 2048
#define NYK 2048
#define NC  (NXK - 1)   // 2047 cells per dim

// ---------------- build: per-cell packed fp16 Hermite record (32 B) ----------------
// rec[cell] = 16 halfs: [f00,f01,f10,f11, gx00..gx11, gy00..gy11, gxy00..gxy11]
// where gx = fx*dx, gy = fy*dy, gxy = fxy*dx*dy  (premultiplied at build time;
// raw fx ~ O(1e4) would lose fp16 accuracy, fx*dx ~ O(1) is safe).
__global__ __launch_bounds__(256) void build_kernel(
    const float* __restrict__ xk, const float* __restrict__ yk,
    const float* __restrict__ f,  const float* __restrict__ fx,
    const float* __restrict__ fy, const float* __restrict__ fxy,
    __half* __restrict__ rec)
{
    int j = blockIdx.x * blockDim.x + threadIdx.x;
    int i = blockIdx.y;
    if (j >= NC) return;

    size_t base = (size_t)i * NYK + j;
    float dx = xk[i + 1] - xk[i];
    float dy = yk[j + 1] - yk[j];
    float dxy = dx * dy;

    union { __half h[16]; float4 v[2]; } r;

    r.h[0]  = __float2half(f[base]);
    r.h[1]  = __float2half(f[base + 1]);
    r.h[2]  = __float2half(f[base + NYK]);
    r.h[3]  = __float2half(f[base + NYK + 1]);

    r.h[4]  = __float2half(fx[base] * dx);
    r.h[5]  = __float2half(fx[base + 1] * dx);
    r.h[6]  = __float2half(fx[base + NYK] * dx);
    r.h[7]  = __float2half(fx[base + NYK + 1] * dx);

    r.h[8]  = __float2half(fy[base] * dy);
    r.h[9]  = __float2half(fy[base + 1] * dy);
    r.h[10] = __float2half(fy[base + NYK] * dy);
    r.h[11] = __float2half(fy[base + NYK + 1] * dy);

    r.h[12] = __float2half(fxy[base] * dxy);
    r.h[13] = __float2half(fxy[base + 1] * dxy);
    r.h[14] = __float2half(fxy[base + NYK] * dxy);
    r.h[15] = __float2half(fxy[base + NYK + 1] * dxy);

    float4* outp = reinterpret_cast<float4*>(rec + ((size_t)i * NC + j) * 16);
    outp[0] = r.v[0];
    outp[1] = r.v[1];
}

// ---------------- gather: one 32 B record per query ----------------
__global__ __launch_bounds__(256) void gather_kernel(
    const float* __restrict__ xq, const float* __restrict__ yq,
    const float* __restrict__ xk, const float* __restrict__ yk,
    const __half* __restrict__ rec,
    float* __restrict__ out, int nq)
{
    int q = blockIdx.x * blockDim.x + threadIdx.x;
    if (q >= nq) return;

    float xv = xq[q];
    float yv = yq[q];

    int il = (int)floorf(xv * (float)(NXK - 1));
    il = min(max(il, 0), NXK - 2);
    while (il < NXK - 2 && xv >= xk[il + 1]) ++il;
    while (il > 0 && xv < xk[il]) --il;

    int jl = (int)floorf(yv * (float)(NYK - 1));
    jl = min(max(jl, 0), NYK - 2);
    while (jl < NYK - 2 && yv >= yk[jl + 1]) ++jl;
    while (jl > 0 && yv < yk[jl]) --jl;

    float x0 = xk[il], x1 = xk[il + 1];
    float dx = x1 - x0;
    float tx = (xv - x0) * ((dx == 0.0f) ? 0.0f : 1.0f / dx);

    float y0 = yk[jl], y1 = yk[jl + 1];
    float dy = y1 - y0;
    float ty = (yv - y0) * ((dy == 0.0f) ? 0.0f : 1.0f / dy);

    // u/v = t-powers through A_CUBIC (note A[3,3] = -1, interpax's matrix)
    float u0 = 1.0f + tx * tx * (2.0f * tx - 3.0f);
    float u1 = tx * tx * (3.0f - 2.0f * tx);
    float u2 = tx * (1.0f + tx * (tx - 2.0f));
    float u3 = -tx * tx * (1.0f + tx);

    float v0 = 1.0f + ty * ty * (2.0f * ty - 3.0f);
    float v1 = ty * ty * (3.0f - 2.0f * ty);
    float v2 = ty * (1.0f + ty * (ty - 2.0f));
    float v3 = -ty * ty * (1.0f + ty);

    size_t cell = (size_t)il * NC + jl;
    const float4* rp = reinterpret_cast<const float4*>(rec) + cell * 2;
    union { float4 v[2]; __half2 h2[8]; } r;
    r.v[0] = rp[0];
    r.v[1] = rp[1];

    // h2[0]=(f00,f01) h2[1]=(f10,f11) h2[2]=(gx00,gx01) h2[3]=(gx10,gx11)
    // h2[4]=(gy00,gy01) h2[5]=(gy10,gy11) h2[6]=(gxy00,gxy01) h2[7]=(gxy10,gxy11)
    float2 a, b;
    a = __half22float2(r.h2[0]); b = __half22float2(r.h2[1]);
    float sf   = u0 * a.x + u2 * a.y + u1 * b.x + u3 * b.y;
    a = __half22float2(r.h2[2]); b = __half22float2(r.h2[3]);
    float sgx  = u0 * a.x + u2 * a.y + u1 * b.x + u3 * b.y;
    a = __half22float2(r.h2[4]); b = __half22float2(r.h2[5]);
    float sgy  = u0 * a.x + u2 * a.y + u1 * b.x + u3 * b.y;
    a = __half22float2(r.h2[6]); b = __half22float2(r.h2[7]);
    float sgxy = u0 * a.x + u2 * a.y + u1 * b.x + u3 * b.y;

    out[q] = v0 * sf + v1 * sgx + v2 * sgy + v3 * sgxy;
}

// ---------------- fallback (round-1 direct gather) ----------------
__global__ __launch_bounds__(256) void interp2d_direct(
    const float* __restrict__ xq, const float* __restrict__ yq,
    const float* __restrict__ xk, const float* __restrict__ yk,
    const float* __restrict__ f,  const float* __restrict__ fx,
    const float* __restrict__ fy, const float* __restrict__ fxy,
    float* __restrict__ out, int nq)
{
    int q = blockIdx.x * blockDim.x + threadIdx.x;
    if (q >= nq) return;

    float xv = xq[q];
    float yv = yq[q];

    int il = (int)floorf(xv * (float)(NXK - 1));
    il = min(max(il, 0), NXK - 2);
    while (il < NXK - 2 && xv >= xk[il + 1]) ++il;
    while (il > 0 && xv < xk[il]) --il;

    int jl = (int)floorf(yv * (float)(NYK - 1));
    jl = min(max(jl, 0), NYK - 2);
    while (jl < NYK - 2 && yv >= yk[jl + 1]) ++jl;
    while (jl > 0 && yv < yk[jl]) --jl;

    float x0 = xk[il], x1 = xk[il + 1];
    float dx = x1 - x0;
    float tx = (xv - x0) * ((dx == 0.0f) ? 0.0f : 1.0f / dx);
    float y0 = yk[jl], y1 = yk[jl + 1];
    float dy = y1 - y0;
    float ty = (yv - y0) * ((dy == 0.0f) ? 0.0f : 1.0f / dy);

    float u0 = 1.0f + tx * tx * (2.0f * tx - 3.0f);
    float u1 = tx * tx * (3.0f - 2.0f * tx);
    float u2 = tx * (1.0f + tx * (tx - 2.0f));
    float u3 = -tx * tx * (1.0f + tx);
    float v0 = 1.0f + ty * ty * (2.0f * ty - 3.0f);
    float v1 = ty * ty * (3.0f - 2.0f * ty);
    float v2 = ty * (1.0f + ty * (ty - 2.0f));
    float v3 = -ty * ty * (1.0f + ty);

    long base = (long)il * NYK + jl;
    const float* p = f + base;
    float sf   = u0 * p[0] + u2 * p[1] + u1 * p[NYK] + u3 * p[NYK + 1];
    p = fx + base;
    float sfx  = u0 * p[0] + u2 * p[1] + u1 * p[NYK] + u3 * p[NYK + 1];
    p = fy + base;
    float sfy  = u0 * p[0] + u2 * p[1] + u1 * p[NYK] + u3 * p[NYK + 1];
    p = fxy + base;
    float sfxy = u0 * p[0] + u2 * p[1] + u1 * p[NYK] + u3 * p[NYK + 1];

    out[q] = v0 * sf + v1 * (sfx * dx) + v2 * (sfy * dy) + v3 * (sfxy * (dx * dy));
}

extern "C" void kernel_launch(void* const* d_in, const int* in_sizes, int n_in,
                              void* d_out, int out_size, void* d_ws, size_t ws_size,
                              hipStream_t stream) {
    const float* xq  = (const float*)d_in[0];
    const float* yq  = (const float*)d_in[1];
    const float* xk  = (const float*)d_in[2];
    const float* yk  = (const float*)d_in[3];
    const float* f   = (const float*)d_in[4];
    const float* fx  = (const float*)d_in[5];
    const float* fy  = (const float*)d_in[6];
    const float* fxy = (const float*)d_in[7];
    float* out = (float*)d_out;

    int nq = in_sizes[0];
    const size_t rec_bytes = (size_t)NC * NC * 16 * sizeof(__half);  // ~134 MB

    if (ws_size >= rec_bytes) {
        __half* rec = (__half*)d_ws;
        dim3 bgrid((NC + 255) / 256, NC);
        build_kernel<<<bgrid, 256, 0, stream>>>(xk, yk, f, fx, fy, fxy, rec);
        int grid = (nq + 255) / 256;
        gather_kernel<<<grid, 256, 0, stream>>>(xq, yq, xk, yk, rec, out, nq);
    } else {
        int grid = (nq + 255) / 256;
        interp2d_direct<<<grid, 256, 0, stream>>>(xq, yq, xk, yk, f, fx, fy, fxy, out, nq);
    }
}